// Round 5
// baseline (917.861 us; speedup 1.0000x reference)
//
#include <hip/hip_runtime.h>

#define BATCH 256
#define TSTEPS 2048
#define NDIM 64
#define DIN 6
#define ALPHA 0.2f
// sqrt(2 * 0.2 * 0.15^2)
#define NSCALE 0.09486832980505137f

// R9: batched-readlane broadcast. R4/R5/R8 all converge at ~600 cyc/step
// despite a 2x spread in instruction count -> the wall is per-element
// latency in the broadcast, not issue. Diagnosis: the compiler pairs
// v_readlane with its dependent v_fma at distance ~2; the VALU-writes-SGPR
// -> VALU-reads-SGPR hazard costs ~8-9 cyc per element (~570 cyc/step).
// Fix: issue 32 readlanes into 32 distinct SGPRs first, THEN the 32
// dependent fmas — every fma reads an SGPR written >=32 instructions
// earlier, so all hazard wait-states are hidden under real issue.
// sched_barrier(0) pins the block boundaries. Two 32-element halves keep
// live SGPRs within budget. No LDS anywhere.
//
// Numerics: BIT-IDENTICAL to the harness-validated R4/R5/R8 kernels —
// same fmaf ops, same order (ax/ay/az/aw over column classes i%4, halves
// i=0..7 then i=8..15 continuing the same accumulators), same drive,
// same combine ((ax+ay)+(az+aw))+d, same relu/blend. Only the transport
// schedule of s changed (same bits).
__device__ __forceinline__ float rdlane(float v, int lane) {
    return __uint_as_float((unsigned)__builtin_amdgcn_readlane((int)__float_as_uint(v), lane));
}

__global__ __launch_bounds__(64, 1) void rnn_scan_kernel(
    const float* __restrict__ u,      // [B, T, DIN]
    const float* __restrict__ noise,  // [B, T, N]
    const float* __restrict__ W_rec,  // [N, N]
    const float* __restrict__ W_in,   // [N, DIN]
    float* __restrict__ states)       // [B, T, N]
{
    const int b = blockIdx.x;
    const int j = threadIdx.x;

    // W_rec row j -> registers (64 VGPRs)
    float4 w4[16];
    const float4* wr = reinterpret_cast<const float4*>(W_rec + j * NDIM);
#pragma unroll
    for (int i = 0; i < 16; ++i) w4[i] = wr[i];

    float win[DIN];
#pragma unroll
    for (int d = 0; d < DIN; ++d) win[d] = W_in[j * DIN + d];

    const float* nb = noise + (size_t)b * TSTEPS * NDIM;
    const float4* ub4 = reinterpret_cast<const float4*>(u + (size_t)b * TSTEPS * DIN);
    float* st = states + (size_t)b * TSTEPS * NDIM;

    float s = 0.0f;
    st[j] = 0.0f;  // states[b, 0, :] = 0

    auto step_body = [&](int t, float nvk, const float* uuf) {
        float ax = 0.0f, ay = 0.0f, az = 0.0f, aw = 0.0f;

        // Half 1: elements 0..31. Batch 32 readlanes (32 SGPRs), fence,
        // then the 32 fmas (chains i=0..7).
        {
            float sv[32];
#pragma unroll
            for (int i = 0; i < 32; ++i) sv[i] = rdlane(s, i);
            __builtin_amdgcn_sched_barrier(0);
#pragma unroll
            for (int i = 0; i < 8; ++i) {
                const float4 wv = w4[i];
                ax = fmaf(wv.x, sv[4 * i + 0], ax);
                ay = fmaf(wv.y, sv[4 * i + 1], ay);
                az = fmaf(wv.z, sv[4 * i + 2], az);
                aw = fmaf(wv.w, sv[4 * i + 3], aw);
            }
        }
        __builtin_amdgcn_sched_barrier(0);
        // Half 2: elements 32..63 (chains i=8..15, same accumulators).
        {
            float sv[32];
#pragma unroll
            for (int i = 0; i < 32; ++i) sv[i] = rdlane(s, 32 + i);
            __builtin_amdgcn_sched_barrier(0);
#pragma unroll
            for (int i = 8; i < 16; ++i) {
                const float4 wv = w4[i];
                ax = fmaf(wv.x, sv[4 * (i - 8) + 0], ax);
                ay = fmaf(wv.y, sv[4 * (i - 8) + 1], ay);
                az = fmaf(wv.z, sv[4 * (i - 8) + 2], az);
                aw = fmaf(wv.w, sv[4 * (i - 8) + 3], aw);
            }
        }

        // Drive (identical to validated kernel)
        float d = NSCALE * nvk;
#pragma unroll
        for (int kk = 0; kk < DIN; ++kk) d = fmaf(win[kk], uuf[kk], d);

        const float acc = ((ax + ay) + (az + aw)) + d;
        s = fmaf(1.0f - ALPHA, s, ALPHA * fmaxf(acc, 0.0f));

        st[(size_t)(t + 1) * NDIM + j] = s;  // fire-and-forget
    };

    // Prefetch buffers: 8 steps of noise (per-lane dword) and u (wave-uniform,
    // 12 float4). A/B ping-pong, guard-free.
    float nva[8], nvb[8];
    float4 uua[12], uub[12];
#pragma unroll
    for (int k = 0; k < 8; ++k) nva[k] = nb[k * NDIM + j];
#pragma unroll
    for (int k = 0; k < 12; ++k) uua[k] = ub4[k];

    auto run8 = [&](int tb, const float* nv, const float4* uu,
                    float* nvN, float4* uuN) {
        const int tpf = tb + 8;
#pragma unroll
        for (int k = 0; k < 8; ++k) nvN[k] = nb[(tpf + k) * NDIM + j];
        const int ubase = tpf * DIN / 4;  // tpf multiple of 8 -> exact
#pragma unroll
        for (int k = 0; k < 12; ++k) uuN[k] = ub4[ubase + k];

        const float* uuf = reinterpret_cast<const float*>(uu);
#pragma unroll
        for (int k = 0; k < 8; ++k) step_body(tb + k, nv[k], uuf + k * DIN);
    };

    // T-1 = 2047 steps: 127*16 (ping-pong pairs) + 8 + 7-step tail.
    int tb = 0;
    for (int it = 0; it < 127; ++it) {
        run8(tb, nva, uua, nvb, uub); tb += 8;   // uses A, refills B
        run8(tb, nvb, uub, nva, uua); tb += 8;   // uses B, refills A
    }
    // tb == 2032; A holds 2032..2039. Prefetch 2040..2047 into B (in-bounds).
    run8(2032, nva, uua, nvb, uub);
    // Tail: steps 2040..2046 (7 steps) from B, no further prefetch.
    {
        const float* uuf = reinterpret_cast<const float*>(uub);
#pragma unroll
        for (int k = 0; k < 7; ++k) step_body(2040 + k, nvb[k], uuf + k * DIN);
    }
}

// out[r, o] = sum_n states[r, n] * W_out[o][n]. Quad scheme (validated):
// 4 lanes per row, 16 contiguous floats per lane, wave covers 16 rows = 4 KB
// contiguous. ~25 us at this grid; the remaining bench-vs-rocprof gap is
// fixed harness overhead (~160 us), proven by R6/R7 single-kernel runs.
__global__ __launch_bounds__(256) void out_proj_kernel(
    const float* __restrict__ states,  // [B*T, N]
    const float* __restrict__ W_out,   // [2, N]
    float* __restrict__ out)           // [B*T, 2]
{
    const int lane = threadIdx.x & 63;
    const int seg = lane & 3;    // which 16-elem segment of the row
    const int rsub = lane >> 2;  // row within the 16-row group

    const size_t wave = (size_t)(blockIdx.x * blockDim.x + threadIdx.x) >> 6;
    const size_t nwaves = ((size_t)gridDim.x * blockDim.x) >> 6;
    const size_t ngroups = (size_t)BATCH * TSTEPS / 16;

    float4 w0[4], w1[4];
    const float4* wo = reinterpret_cast<const float4*>(W_out);
#pragma unroll
    for (int i = 0; i < 4; ++i) {
        w0[i] = wo[seg * 4 + i];       // W_out[0][seg*16 + i*4 ..]
        w1[i] = wo[16 + seg * 4 + i];  // W_out[1][seg*16 + i*4 ..]
    }

    for (size_t g = wave; g < ngroups; g += nwaves) {
        const size_t r = g * 16 + rsub;
        const float4* sp = reinterpret_cast<const float4*>(states + r * NDIM + seg * 16);
        float p0 = 0.0f, p1 = 0.0f;
#pragma unroll
        for (int i = 0; i < 4; ++i) {
            const float4 sv = sp[i];
            p0 = fmaf(sv.x, w0[i].x, p0); p0 = fmaf(sv.y, w0[i].y, p0);
            p0 = fmaf(sv.z, w0[i].z, p0); p0 = fmaf(sv.w, w0[i].w, p0);
            p1 = fmaf(sv.x, w1[i].x, p1); p1 = fmaf(sv.y, w1[i].y, p1);
            p1 = fmaf(sv.z, w1[i].z, p1); p1 = fmaf(sv.w, w1[i].w, p1);
        }
        p0 += __shfl_xor(p0, 1); p0 += __shfl_xor(p0, 2);
        p1 += __shfl_xor(p1, 1); p1 += __shfl_xor(p1, 2);
        if (seg == 0) {
            reinterpret_cast<float2*>(out)[r] = make_float2(p0, p1);
        }
    }
}

extern "C" void kernel_launch(void* const* d_in, const int* in_sizes, int n_in,
                              void* d_out, int out_size, void* d_ws, size_t ws_size,
                              hipStream_t stream) {
    const float* u     = (const float*)d_in[0];
    const float* noise = (const float*)d_in[1];
    const float* W_rec = (const float*)d_in[2];
    const float* W_in  = (const float*)d_in[3];
    const float* W_out = (const float*)d_in[4];

    float* states = (float*)d_out;                           // B*T*N floats
    float* out    = states + (size_t)BATCH * TSTEPS * NDIM;  // B*T*2 floats

    rnn_scan_kernel<<<BATCH, 64, 0, stream>>>(u, noise, W_rec, W_in, states);
    out_proj_kernel<<<2048, 256, 0, stream>>>(states, W_out, out);
}